// Round 1
// baseline (989.640 us; speedup 1.0000x reference)
//
#include <hip/hip_runtime.h>
#include <math.h>

#define N_NODES 100000
#define NF 128

// ---------------- CSR build ----------------

__global__ __launch_bounds__(256) void count_kernel(const int* __restrict__ dst,
                                                    int* __restrict__ cnt, int e) {
    int i = blockIdx.x * 256 + threadIdx.x;
    if (i < e) {
        int d = dst[i];
        if ((unsigned)d < N_NODES) atomicAdd(&cnt[d], 1);
    }
}

// single-block exclusive scan over N=100k counts; also seeds cursor and offs[n]
__global__ __launch_bounds__(1024) void scan_kernel(const int* __restrict__ cnt,
                                                    int* __restrict__ offs,
                                                    int* __restrict__ cur, int n) {
    __shared__ int sdata[1024];
    int tid = threadIdx.x;
    int per = (n + 1023) >> 10;
    int begin = tid * per; if (begin > n) begin = n;
    int end = begin + per; if (end > n) end = n;
    int sum = 0;
    for (int i = begin; i < end; ++i) sum += cnt[i];
    sdata[tid] = sum;
    __syncthreads();
    // Hillis-Steele inclusive scan of 1024 thread sums
    for (int off = 1; off < 1024; off <<= 1) {
        int v = (tid >= off) ? sdata[tid - off] : 0;
        __syncthreads();
        sdata[tid] += v;
        __syncthreads();
    }
    int run = (tid == 0) ? 0 : sdata[tid - 1];
    for (int i = begin; i < end; ++i) {
        offs[i] = run; cur[i] = run;
        run += cnt[i];
    }
    if (tid == 1023) offs[n] = sdata[1023];
}

__global__ __launch_bounds__(256) void dinv_kernel(const int* __restrict__ cnt,
                                                   float* __restrict__ dinv, int n) {
    int i = blockIdx.x * 256 + threadIdx.x;
    if (i < n) dinv[i] = 1.0f / sqrtf((float)cnt[i] + 1.0f);  // deg = in-count + self-loop
}

__global__ __launch_bounds__(256) void fill_kernel(const int* __restrict__ src,
                                                   const int* __restrict__ dst,
                                                   int* __restrict__ cur,
                                                   int* __restrict__ bsrc, int e) {
    int i = blockIdx.x * 256 + threadIdx.x;
    if (i < e) {
        int d = dst[i];
        if ((unsigned)d < N_NODES) {
            int p = atomicAdd(&cur[d], 1);
            bsrc[p] = src[i];
        }
    }
}

// ---------------- GEMM: Y[n,128] = X[n,128] @ W[128,128] (fp32 vector ALU) ----------------
// 64 rows/block, 256 threads, K staged in 32-chunks. LDS = 16KB (W chunk) + 8.4KB (X tile).
// Thread tile: 4 rows x 8 cols (two float4 column groups at c and 64+c).
__global__ __launch_bounds__(256) void gemm_kernel(const float* __restrict__ X,
                                                   const float* __restrict__ W,
                                                   float* __restrict__ Y, int nrows) {
    __shared__ float sW[32 * 128];   // [kk][c]
    __shared__ float sX[64 * 33];    // [r][kk], stride 33 -> conflict-free scalar access
    int tid = threadIdx.x;
    long row0 = (long)blockIdx.x * 64;
    int rg = tid >> 4, cg = tid & 15;
    int rowb = rg * 4;
    int c0 = cg * 4, c1 = 64 + cg * 4;

    float acc[4][8];
#pragma unroll
    for (int i = 0; i < 4; ++i)
#pragma unroll
        for (int j = 0; j < 8; ++j) acc[i][j] = 0.f;

    for (int k0 = 0; k0 < 128; k0 += 32) {
        // stage W chunk: rows k0..k0+31 = 4096 floats = 1024 float4
#pragma unroll
        for (int i = 0; i < 4; ++i) {
            int idx = i * 256 + tid;
            ((float4*)sW)[idx] = ((const float4*)(W + (long)k0 * 128))[idx];
        }
        // stage X tile: 64 rows x 32 cols = 512 float4
#pragma unroll
        for (int i = 0; i < 2; ++i) {
            int idx = i * 256 + tid;      // 0..511
            int r = idx >> 3;             // 0..63
            int q = idx & 7;              // float4 within the 32-col chunk
            float4 v = make_float4(0.f, 0.f, 0.f, 0.f);
            long rr = row0 + r;
            if (rr < nrows) v = *(const float4*)&X[rr * 128 + k0 + q * 4];
            sX[r * 33 + q * 4 + 0] = v.x;
            sX[r * 33 + q * 4 + 1] = v.y;
            sX[r * 33 + q * 4 + 2] = v.z;
            sX[r * 33 + q * 4 + 3] = v.w;
        }
        __syncthreads();
#pragma unroll 8
        for (int kk = 0; kk < 32; ++kk) {
            float4 w0 = *(const float4*)&sW[kk * 128 + c0];
            float4 w1 = *(const float4*)&sW[kk * 128 + c1];
            float xr[4];
#pragma unroll
            for (int i = 0; i < 4; ++i) xr[i] = sX[(rowb + i) * 33 + kk];
#pragma unroll
            for (int i = 0; i < 4; ++i) {
                acc[i][0] = fmaf(xr[i], w0.x, acc[i][0]);
                acc[i][1] = fmaf(xr[i], w0.y, acc[i][1]);
                acc[i][2] = fmaf(xr[i], w0.z, acc[i][2]);
                acc[i][3] = fmaf(xr[i], w0.w, acc[i][3]);
                acc[i][4] = fmaf(xr[i], w1.x, acc[i][4]);
                acc[i][5] = fmaf(xr[i], w1.y, acc[i][5]);
                acc[i][6] = fmaf(xr[i], w1.z, acc[i][6]);
                acc[i][7] = fmaf(xr[i], w1.w, acc[i][7]);
            }
        }
        __syncthreads();
    }
#pragma unroll
    for (int i = 0; i < 4; ++i) {
        long r = row0 + rowb + i;
        if (r < nrows) {
            *(float4*)&Y[r * 128 + c0] = make_float4(acc[i][0], acc[i][1], acc[i][2], acc[i][3]);
            *(float4*)&Y[r * 128 + c1] = make_float4(acc[i][4], acc[i][5], acc[i][6], acc[i][7]);
        }
    }
}

// ---------------- Aggregation: out[n] = relu(sum_e norm*g[src] + g[n]*dinv^2 + b) ----------------
// One block (128 threads = one column each) per node; CSR gather, no atomics.
__global__ __launch_bounds__(128) void agg_kernel(const float* __restrict__ g,
                                                  const int* __restrict__ offs,
                                                  const int* __restrict__ bsrc,
                                                  const float* __restrict__ dinv,
                                                  const float* __restrict__ bias,
                                                  float* __restrict__ out, int n) {
    int node = blockIdx.x;
    int c = threadIdx.x;
    int e0 = offs[node], e1 = offs[node + 1];
    float din = dinv[node];
    float acc = g[(long)node * 128 + c] * (din * din);   // self-loop term
    for (int e = e0; e < e1; ++e) {
        int s = bsrc[e];
        float w = dinv[s] * din;
        acc = fmaf(g[(long)s * 128 + c], w, acc);
    }
    acc += bias[c];
    out[(long)node * 128 + c] = fmaxf(acc, 0.f);
}

// ---------------- Readout: combined = [h[0], mean_{e: dst==0} h[src]] ; out = combined @ fcw + fcb
__global__ __launch_bounds__(256) void final_kernel(const float* __restrict__ h,
                                                    const int* __restrict__ offs,
                                                    const int* __restrict__ bsrc,
                                                    const float* __restrict__ fcw,
                                                    const float* __restrict__ fcb,
                                                    float* __restrict__ out) {
    __shared__ float sred[256];
    int t = threadIdx.x;
    int e0 = offs[0], e1 = offs[1];
    float val;
    if (t < 128) {
        val = h[t] * fcw[t];
    } else {
        int col = t - 128;
        float s = 0.f;
        for (int e = e0; e < e1; ++e) s += h[(long)bsrc[e] * 128 + col];
        int cnt = e1 - e0; if (cnt < 1) cnt = 1;
        val = (s / (float)cnt) * fcw[t];
    }
    sred[t] = val;
    __syncthreads();
    for (int off = 128; off > 0; off >>= 1) {
        if (t < off) sred[t] += sred[t + off];
        __syncthreads();
    }
    if (t == 0) out[0] = sred[0] + fcb[0];
}

// ---------------- launch ----------------

extern "C" void kernel_launch(void* const* d_in, const int* in_sizes, int n_in,
                              void* d_out, int out_size, void* d_ws, size_t ws_size,
                              hipStream_t stream) {
    const float* x   = (const float*)d_in[0];
    const int*   ei  = (const int*)d_in[1];
    // d_in[2] = concentration (unused by the reference)
    const float* w1  = (const float*)d_in[3];
    const float* b1  = (const float*)d_in[4];
    const float* w2  = (const float*)d_in[5];
    const float* b2  = (const float*)d_in[6];
    const float* fcw = (const float*)d_in[7];
    const float* fcb = (const float*)d_in[8];

    const int n = N_NODES;
    const int e = in_sizes[1] / 2;
    const int* src = ei;
    const int* dst = ei + e;

    char* ws = (char*)d_ws;
    size_t off = 0;
    auto take = [&](size_t bytes) -> void* {
        void* p = ws + off;
        off += (bytes + 255) & ~(size_t)255;
        return p;
    };
    int*   cnt  = (int*)  take((size_t)n * 4);
    int*   offs = (int*)  take((size_t)(n + 1) * 4);
    int*   cur  = (int*)  take((size_t)n * 4);
    float* dinv = (float*)take((size_t)n * 4);
    int*   bsrc = (int*)  take((size_t)e * 4);
    float* bufA = (float*)take((size_t)n * NF * 4);
    float* bufB = (float*)take((size_t)n * NF * 4);
    (void)ws_size;

    hipMemsetAsync(cnt, 0, (size_t)n * 4, stream);
    count_kernel<<<(e + 255) / 256, 256, 0, stream>>>(dst, cnt, e);
    scan_kernel<<<1, 1024, 0, stream>>>(cnt, offs, cur, n);
    dinv_kernel<<<(n + 255) / 256, 256, 0, stream>>>(cnt, dinv, n);
    fill_kernel<<<(e + 255) / 256, 256, 0, stream>>>(src, dst, cur, bsrc, e);

    // layer 1: g = x @ w1 ; h1 = relu(agg(g) + b1)
    gemm_kernel<<<(n + 63) / 64, 256, 0, stream>>>(x, w1, bufA, n);
    agg_kernel<<<n, 128, 0, stream>>>(bufA, offs, bsrc, dinv, b1, bufB, n);
    // layer 2: g2 = h1 @ w2 ; h2 = relu(agg(g2) + b2)
    gemm_kernel<<<(n + 63) / 64, 256, 0, stream>>>(bufB, w2, bufA, n);
    agg_kernel<<<n, 128, 0, stream>>>(bufA, offs, bsrc, dinv, b2, bufB, n);
    // readout
    final_kernel<<<1, 256, 0, stream>>>(bufB, offs, bsrc, fcw, fcb, (float*)d_out);
}

// Round 2
// 624.279 us; speedup vs baseline: 1.5853x; 1.5853x over previous
//
#include <hip/hip_runtime.h>
#include <math.h>

#define N_NODES 100000
#define NF 128

// ---------------- CSR build ----------------

__global__ __launch_bounds__(256) void count_kernel(const int* __restrict__ dst,
                                                    int* __restrict__ cnt, int e) {
    int i = blockIdx.x * 256 + threadIdx.x;
    int base = i * 4;
    if (base + 3 < e) {
        int4 d = ((const int4*)dst)[i];
        atomicAdd(&cnt[d.x], 1);
        atomicAdd(&cnt[d.y], 1);
        atomicAdd(&cnt[d.z], 1);
        atomicAdd(&cnt[d.w], 1);
    } else {
        for (int j = base; j < e; ++j) atomicAdd(&cnt[dst[j]], 1);
    }
}

// ---- hierarchical scan: 100k counts -> offs (exclusive), cur copy, offs[n]=total ----
// Phase A: per-block (1024 elems) sums
__global__ __launch_bounds__(256) void blocksum_kernel(const int* __restrict__ cnt,
                                                       int* __restrict__ bsum, int n) {
    __shared__ int sd[256];
    int tid = threadIdx.x;
    int base = blockIdx.x * 1024 + tid * 4;
    int s = 0;
    if (base + 3 < n) {
        int4 c = *(const int4*)&cnt[base];
        s = c.x + c.y + c.z + c.w;
    } else {
        for (int j = base; j < n; ++j) s += cnt[j];
    }
    sd[tid] = s;
    __syncthreads();
    for (int off = 128; off > 0; off >>= 1) {
        if (tid < off) sd[tid] += sd[tid + off];
        __syncthreads();
    }
    if (tid == 0) bsum[blockIdx.x] = sd[0];
}

// Phase B: single block scans <=128 block sums (exclusive), writes offs[n]=total
__global__ __launch_bounds__(128) void bscan_kernel(const int* __restrict__ bsum,
                                                    int* __restrict__ bpre,
                                                    int* __restrict__ offs,
                                                    int nblk, int n) {
    __shared__ int sd[128];
    int tid = threadIdx.x;
    int v = (tid < nblk) ? bsum[tid] : 0;
    sd[tid] = v;
    __syncthreads();
    for (int off = 1; off < 128; off <<= 1) {
        int t = (tid >= off) ? sd[tid - off] : 0;
        __syncthreads();
        sd[tid] += t;
        __syncthreads();
    }
    if (tid < nblk) bpre[tid] = sd[tid] - v;
    if (tid == 0) offs[n] = sd[127];
}

// Phase C: per-block local scan + block prefix -> offs, cur
__global__ __launch_bounds__(256) void scatter_offs_kernel(const int* __restrict__ cnt,
                                                           const int* __restrict__ bpre,
                                                           int* __restrict__ offs,
                                                           int* __restrict__ cur, int n) {
    __shared__ int sd[256];
    int tid = threadIdx.x;
    int base = blockIdx.x * 1024 + tid * 4;
    int c[4] = {0, 0, 0, 0};
    if (base + 3 < n) {
        int4 cc = *(const int4*)&cnt[base];
        c[0] = cc.x; c[1] = cc.y; c[2] = cc.z; c[3] = cc.w;
    } else {
        for (int j = 0; j < 4; ++j) if (base + j < n) c[j] = cnt[base + j];
    }
    int ts = c[0] + c[1] + c[2] + c[3];
    sd[tid] = ts;
    __syncthreads();
    for (int off = 1; off < 256; off <<= 1) {
        int t = (tid >= off) ? sd[tid - off] : 0;
        __syncthreads();
        sd[tid] += t;
        __syncthreads();
    }
    int run = bpre[blockIdx.x] + sd[tid] - ts;
    for (int j = 0; j < 4; ++j) {
        int idx = base + j;
        if (idx < n) { offs[idx] = run; cur[idx] = run; run += c[j]; }
    }
}

__global__ __launch_bounds__(256) void dinv_kernel(const int* __restrict__ cnt,
                                                   float* __restrict__ dinv, int n) {
    int i = blockIdx.x * 256 + threadIdx.x;
    if (i < n) dinv[i] = 1.0f / sqrtf((float)cnt[i] + 1.0f);  // deg = in-count + self-loop
}

// fill buckets; also precompute per-edge weight wei = dinv[src]*dinv[dst]
__global__ __launch_bounds__(256) void fill_kernel(const int* __restrict__ src,
                                                   const int* __restrict__ dst,
                                                   const float* __restrict__ dinv,
                                                   int* __restrict__ cur,
                                                   int* __restrict__ bsrc,
                                                   float* __restrict__ wei, int e) {
    int i = blockIdx.x * 256 + threadIdx.x;
    int base = i * 4;
    if (base + 3 < e) {
        int4 s4 = ((const int4*)src)[i];
        int4 d4 = ((const int4*)dst)[i];
        int ss[4] = {s4.x, s4.y, s4.z, s4.w};
        int dd[4] = {d4.x, d4.y, d4.z, d4.w};
#pragma unroll
        for (int j = 0; j < 4; ++j) {
            int p = atomicAdd(&cur[dd[j]], 1);
            bsrc[p] = ss[j];
            wei[p] = dinv[ss[j]] * dinv[dd[j]];
        }
    } else {
        for (int j = base; j < e; ++j) {
            int s = src[j], d = dst[j];
            int p = atomicAdd(&cur[d], 1);
            bsrc[p] = s;
            wei[p] = dinv[s] * dinv[d];
        }
    }
}

// ---------------- GEMM: Y[n,128] = X[n,128] @ W[128,128] (fp32 vector ALU) ----------------
__global__ __launch_bounds__(256) void gemm_kernel(const float* __restrict__ X,
                                                   const float* __restrict__ W,
                                                   float* __restrict__ Y, int nrows) {
    __shared__ float sW[32 * 128];   // [kk][c]
    __shared__ float sX[64 * 33];    // [r][kk]
    int tid = threadIdx.x;
    long row0 = (long)blockIdx.x * 64;
    int rg = tid >> 4, cg = tid & 15;
    int rowb = rg * 4;
    int c0 = cg * 4, c1 = 64 + cg * 4;

    float acc[4][8];
#pragma unroll
    for (int i = 0; i < 4; ++i)
#pragma unroll
        for (int j = 0; j < 8; ++j) acc[i][j] = 0.f;

    for (int k0 = 0; k0 < 128; k0 += 32) {
#pragma unroll
        for (int i = 0; i < 4; ++i) {
            int idx = i * 256 + tid;
            ((float4*)sW)[idx] = ((const float4*)(W + (long)k0 * 128))[idx];
        }
#pragma unroll
        for (int i = 0; i < 2; ++i) {
            int idx = i * 256 + tid;
            int r = idx >> 3;
            int q = idx & 7;
            float4 v = make_float4(0.f, 0.f, 0.f, 0.f);
            long rr = row0 + r;
            if (rr < nrows) v = *(const float4*)&X[rr * 128 + k0 + q * 4];
            sX[r * 33 + q * 4 + 0] = v.x;
            sX[r * 33 + q * 4 + 1] = v.y;
            sX[r * 33 + q * 4 + 2] = v.z;
            sX[r * 33 + q * 4 + 3] = v.w;
        }
        __syncthreads();
#pragma unroll 8
        for (int kk = 0; kk < 32; ++kk) {
            float4 w0 = *(const float4*)&sW[kk * 128 + c0];
            float4 w1 = *(const float4*)&sW[kk * 128 + c1];
            float xr[4];
#pragma unroll
            for (int i = 0; i < 4; ++i) xr[i] = sX[(rowb + i) * 33 + kk];
#pragma unroll
            for (int i = 0; i < 4; ++i) {
                acc[i][0] = fmaf(xr[i], w0.x, acc[i][0]);
                acc[i][1] = fmaf(xr[i], w0.y, acc[i][1]);
                acc[i][2] = fmaf(xr[i], w0.z, acc[i][2]);
                acc[i][3] = fmaf(xr[i], w0.w, acc[i][3]);
                acc[i][4] = fmaf(xr[i], w1.x, acc[i][4]);
                acc[i][5] = fmaf(xr[i], w1.y, acc[i][5]);
                acc[i][6] = fmaf(xr[i], w1.z, acc[i][6]);
                acc[i][7] = fmaf(xr[i], w1.w, acc[i][7]);
            }
        }
        __syncthreads();
    }
#pragma unroll
    for (int i = 0; i < 4; ++i) {
        long r = row0 + rowb + i;
        if (r < nrows) {
            *(float4*)&Y[r * 128 + c0] = make_float4(acc[i][0], acc[i][1], acc[i][2], acc[i][3]);
            *(float4*)&Y[r * 128 + c1] = make_float4(acc[i][4], acc[i][5], acc[i][6], acc[i][7]);
        }
    }
}

// ---------------- Aggregation: one WAVE per node, float2 per lane, no block sync ----------------
__global__ __launch_bounds__(256) void agg_kernel(const float* __restrict__ g,
                                                  const int* __restrict__ offs,
                                                  const int* __restrict__ bsrc,
                                                  const float* __restrict__ wei,
                                                  const float* __restrict__ dinv,
                                                  const float* __restrict__ bias,
                                                  float* __restrict__ out, int n) {
    int wid = threadIdx.x >> 6;
    int lane = threadIdx.x & 63;
    int node = blockIdx.x * 4 + wid;
    if (node >= n) return;
    int e0 = offs[node], e1 = offs[node + 1];
    float din = dinv[node];
    float2 gs = *(const float2*)&g[(long)node * 128 + lane * 2];
    float accx = gs.x * (din * din);   // self-loop term
    float accy = gs.y * (din * din);
    int e = e0;
    for (; e + 1 < e1; e += 2) {
        int s0 = bsrc[e], s1 = bsrc[e + 1];
        float w0 = wei[e], w1 = wei[e + 1];
        float2 a0 = *(const float2*)&g[(long)s0 * 128 + lane * 2];
        float2 a1 = *(const float2*)&g[(long)s1 * 128 + lane * 2];
        accx = fmaf(a0.x, w0, accx);
        accy = fmaf(a0.y, w0, accy);
        accx = fmaf(a1.x, w1, accx);
        accy = fmaf(a1.y, w1, accy);
    }
    if (e < e1) {
        int s = bsrc[e];
        float w = wei[e];
        float2 a = *(const float2*)&g[(long)s * 128 + lane * 2];
        accx = fmaf(a.x, w, accx);
        accy = fmaf(a.y, w, accy);
    }
    float2 b2 = *(const float2*)&bias[lane * 2];
    float2 o;
    o.x = fmaxf(accx + b2.x, 0.f);
    o.y = fmaxf(accy + b2.y, 0.f);
    *(float2*)&out[(long)node * 128 + lane * 2] = o;
}

// ---------------- Readout ----------------
__global__ __launch_bounds__(256) void final_kernel(const float* __restrict__ h,
                                                    const int* __restrict__ offs,
                                                    const int* __restrict__ bsrc,
                                                    const float* __restrict__ fcw,
                                                    const float* __restrict__ fcb,
                                                    float* __restrict__ out) {
    __shared__ float sred[256];
    int t = threadIdx.x;
    int e0 = offs[0], e1 = offs[1];
    float val;
    if (t < 128) {
        val = h[t] * fcw[t];
    } else {
        int col = t - 128;
        float s = 0.f;
        for (int e = e0; e < e1; ++e) s += h[(long)bsrc[e] * 128 + col];
        int cnt = e1 - e0; if (cnt < 1) cnt = 1;
        val = (s / (float)cnt) * fcw[t];
    }
    sred[t] = val;
    __syncthreads();
    for (int off = 128; off > 0; off >>= 1) {
        if (t < off) sred[t] += sred[t + off];
        __syncthreads();
    }
    if (t == 0) out[0] = sred[0] + fcb[0];
}

// ---------------- launch ----------------

extern "C" void kernel_launch(void* const* d_in, const int* in_sizes, int n_in,
                              void* d_out, int out_size, void* d_ws, size_t ws_size,
                              hipStream_t stream) {
    const float* x   = (const float*)d_in[0];
    const int*   ei  = (const int*)d_in[1];
    const float* w1  = (const float*)d_in[3];
    const float* b1  = (const float*)d_in[4];
    const float* w2  = (const float*)d_in[5];
    const float* b2  = (const float*)d_in[6];
    const float* fcw = (const float*)d_in[7];
    const float* fcb = (const float*)d_in[8];

    const int n = N_NODES;
    const int e = in_sizes[1] / 2;
    const int* src = ei;
    const int* dst = ei + e;

    char* ws = (char*)d_ws;
    size_t off = 0;
    auto take = [&](size_t bytes) -> void* {
        void* p = ws + off;
        off += (bytes + 255) & ~(size_t)255;
        return p;
    };
    const int nblk = (n + 1023) / 1024;   // 98
    int*   cnt  = (int*)  take((size_t)n * 4);
    int*   offs = (int*)  take((size_t)(n + 1) * 4);
    int*   cur  = (int*)  take((size_t)n * 4);
    float* dinv = (float*)take((size_t)n * 4);
    int*   bsum = (int*)  take((size_t)nblk * 4);
    int*   bpre = (int*)  take((size_t)nblk * 4);
    int*   bsrc = (int*)  take((size_t)e * 4);
    float* wei  = (float*)take((size_t)e * 4);
    float* bufA = (float*)take((size_t)n * NF * 4);
    float* bufB = (float*)take((size_t)n * NF * 4);
    (void)ws_size;

    hipMemsetAsync(cnt, 0, (size_t)n * 4, stream);
    count_kernel<<<(e / 4 + 255) / 256, 256, 0, stream>>>(dst, cnt, e);
    blocksum_kernel<<<nblk, 256, 0, stream>>>(cnt, bsum, n);
    bscan_kernel<<<1, 128, 0, stream>>>(bsum, bpre, offs, nblk, n);
    scatter_offs_kernel<<<nblk, 256, 0, stream>>>(cnt, bpre, offs, cur, n);
    dinv_kernel<<<(n + 255) / 256, 256, 0, stream>>>(cnt, dinv, n);
    fill_kernel<<<(e / 4 + 255) / 256, 256, 0, stream>>>(src, dst, dinv, cur, bsrc, wei, e);

    // layer 1: g = x @ w1 ; h1 = relu(agg(g) + b1)
    gemm_kernel<<<(n + 63) / 64, 256, 0, stream>>>(x, w1, bufA, n);
    agg_kernel<<<(n + 3) / 4, 256, 0, stream>>>(bufA, offs, bsrc, wei, dinv, b1, bufB, n);
    // layer 2: g2 = h1 @ w2 ; h2 = relu(agg(g2) + b2)
    gemm_kernel<<<(n + 63) / 64, 256, 0, stream>>>(bufB, w2, bufA, n);
    agg_kernel<<<(n + 3) / 4, 256, 0, stream>>>(bufA, offs, bsrc, wei, dinv, b2, bufB, n);
    // readout
    final_kernel<<<1, 256, 0, stream>>>(bufB, offs, bsrc, fcw, fcb, (float*)d_out);
}

// Round 3
// 590.156 us; speedup vs baseline: 1.6769x; 1.0578x over previous
//
#include <hip/hip_runtime.h>
#include <math.h>

#define N_NODES 100000
#define NF 128

// ---------------- CSR build ----------------

__global__ __launch_bounds__(256) void count_kernel(const int* __restrict__ dst,
                                                    int* __restrict__ cnt, int e) {
    int i = blockIdx.x * 256 + threadIdx.x;
    int base = i * 4;
    if (base + 3 < e) {
        int4 d = ((const int4*)dst)[i];
        atomicAdd(&cnt[d.x], 1);
        atomicAdd(&cnt[d.y], 1);
        atomicAdd(&cnt[d.z], 1);
        atomicAdd(&cnt[d.w], 1);
    } else {
        for (int j = base; j < e; ++j) atomicAdd(&cnt[dst[j]], 1);
    }
}

// ---- hierarchical scan ----
__global__ __launch_bounds__(256) void blocksum_kernel(const int* __restrict__ cnt,
                                                       int* __restrict__ bsum, int n) {
    __shared__ int sd[256];
    int tid = threadIdx.x;
    int base = blockIdx.x * 1024 + tid * 4;
    int s = 0;
    if (base + 3 < n) {
        int4 c = *(const int4*)&cnt[base];
        s = c.x + c.y + c.z + c.w;
    } else {
        for (int j = base; j < n; ++j) s += cnt[j];
    }
    sd[tid] = s;
    __syncthreads();
    for (int off = 128; off > 0; off >>= 1) {
        if (tid < off) sd[tid] += sd[tid + off];
        __syncthreads();
    }
    if (tid == 0) bsum[blockIdx.x] = sd[0];
}

__global__ __launch_bounds__(128) void bscan_kernel(const int* __restrict__ bsum,
                                                    int* __restrict__ bpre,
                                                    int* __restrict__ offs,
                                                    int nblk, int n) {
    __shared__ int sd[128];
    int tid = threadIdx.x;
    int v = (tid < nblk) ? bsum[tid] : 0;
    sd[tid] = v;
    __syncthreads();
    for (int off = 1; off < 128; off <<= 1) {
        int t = (tid >= off) ? sd[tid - off] : 0;
        __syncthreads();
        sd[tid] += t;
        __syncthreads();
    }
    if (tid < nblk) bpre[tid] = sd[tid] - v;
    if (tid == 0) offs[n] = sd[127];
}

__global__ __launch_bounds__(256) void scatter_offs_kernel(const int* __restrict__ cnt,
                                                           const int* __restrict__ bpre,
                                                           int* __restrict__ offs,
                                                           int* __restrict__ cur, int n) {
    __shared__ int sd[256];
    int tid = threadIdx.x;
    int base = blockIdx.x * 1024 + tid * 4;
    int c[4] = {0, 0, 0, 0};
    if (base + 3 < n) {
        int4 cc = *(const int4*)&cnt[base];
        c[0] = cc.x; c[1] = cc.y; c[2] = cc.z; c[3] = cc.w;
    } else {
        for (int j = 0; j < 4; ++j) if (base + j < n) c[j] = cnt[base + j];
    }
    int ts = c[0] + c[1] + c[2] + c[3];
    sd[tid] = ts;
    __syncthreads();
    for (int off = 1; off < 256; off <<= 1) {
        int t = (tid >= off) ? sd[tid - off] : 0;
        __syncthreads();
        sd[tid] += t;
        __syncthreads();
    }
    int run = bpre[blockIdx.x] + sd[tid] - ts;
    for (int j = 0; j < 4; ++j) {
        int idx = base + j;
        if (idx < n) { offs[idx] = run; cur[idx] = run; run += c[j]; }
    }
}

__global__ __launch_bounds__(256) void dinv_kernel(const int* __restrict__ cnt,
                                                   float* __restrict__ dinv, int n) {
    int i = blockIdx.x * 256 + threadIdx.x;
    if (i < n) dinv[i] = 1.0f / sqrtf((float)cnt[i] + 1.0f);
}

__global__ __launch_bounds__(256) void fill_kernel(const int* __restrict__ src,
                                                   const int* __restrict__ dst,
                                                   const float* __restrict__ dinv,
                                                   int* __restrict__ cur,
                                                   int* __restrict__ bsrc,
                                                   float* __restrict__ wei, int e) {
    int i = blockIdx.x * 256 + threadIdx.x;
    int base = i * 4;
    if (base + 3 < e) {
        int4 s4 = ((const int4*)src)[i];
        int4 d4 = ((const int4*)dst)[i];
        int ss[4] = {s4.x, s4.y, s4.z, s4.w};
        int dd[4] = {d4.x, d4.y, d4.z, d4.w};
#pragma unroll
        for (int j = 0; j < 4; ++j) {
            int p = atomicAdd(&cur[dd[j]], 1);
            bsrc[p] = ss[j];
            wei[p] = dinv[ss[j]] * dinv[dd[j]];
        }
    } else {
        for (int j = base; j < e; ++j) {
            int s = src[j], d = dst[j];
            int p = atomicAdd(&cur[d], 1);
            bsrc[p] = s;
            wei[p] = dinv[s] * dinv[d];
        }
    }
}

// ---------------- GEMM: Y[n,128] = X[n,128] @ W[128,128] (fp32 vector ALU) ----------------
__global__ __launch_bounds__(256) void gemm_kernel(const float* __restrict__ X,
                                                   const float* __restrict__ W,
                                                   float* __restrict__ Y, int nrows) {
    __shared__ float sW[32 * 128];   // [kk][c]
    __shared__ float sX[64 * 33];    // [r][kk]
    int tid = threadIdx.x;
    long row0 = (long)blockIdx.x * 64;
    int rg = tid >> 4, cg = tid & 15;
    int rowb = rg * 4;
    int c0 = cg * 4, c1 = 64 + cg * 4;

    float acc[4][8];
#pragma unroll
    for (int i = 0; i < 4; ++i)
#pragma unroll
        for (int j = 0; j < 8; ++j) acc[i][j] = 0.f;

    for (int k0 = 0; k0 < 128; k0 += 32) {
#pragma unroll
        for (int i = 0; i < 4; ++i) {
            int idx = i * 256 + tid;
            ((float4*)sW)[idx] = ((const float4*)(W + (long)k0 * 128))[idx];
        }
#pragma unroll
        for (int i = 0; i < 2; ++i) {
            int idx = i * 256 + tid;
            int r = idx >> 3;
            int q = idx & 7;
            float4 v = make_float4(0.f, 0.f, 0.f, 0.f);
            long rr = row0 + r;
            if (rr < nrows) v = *(const float4*)&X[rr * 128 + k0 + q * 4];
            sX[r * 33 + q * 4 + 0] = v.x;
            sX[r * 33 + q * 4 + 1] = v.y;
            sX[r * 33 + q * 4 + 2] = v.z;
            sX[r * 33 + q * 4 + 3] = v.w;
        }
        __syncthreads();
#pragma unroll 8
        for (int kk = 0; kk < 32; ++kk) {
            float4 w0 = *(const float4*)&sW[kk * 128 + c0];
            float4 w1 = *(const float4*)&sW[kk * 128 + c1];
            float xr[4];
#pragma unroll
            for (int i = 0; i < 4; ++i) xr[i] = sX[(rowb + i) * 33 + kk];
#pragma unroll
            for (int i = 0; i < 4; ++i) {
                acc[i][0] = fmaf(xr[i], w0.x, acc[i][0]);
                acc[i][1] = fmaf(xr[i], w0.y, acc[i][1]);
                acc[i][2] = fmaf(xr[i], w0.z, acc[i][2]);
                acc[i][3] = fmaf(xr[i], w0.w, acc[i][3]);
                acc[i][4] = fmaf(xr[i], w1.x, acc[i][4]);
                acc[i][5] = fmaf(xr[i], w1.y, acc[i][5]);
                acc[i][6] = fmaf(xr[i], w1.z, acc[i][6]);
                acc[i][7] = fmaf(xr[i], w1.w, acc[i][7]);
            }
        }
        __syncthreads();
    }
#pragma unroll
    for (int i = 0; i < 4; ++i) {
        long r = row0 + rowb + i;
        if (r < nrows) {
            *(float4*)&Y[r * 128 + c0] = make_float4(acc[i][0], acc[i][1], acc[i][2], acc[i][3]);
            *(float4*)&Y[r * 128 + c1] = make_float4(acc[i][4], acc[i][5], acc[i][6], acc[i][7]);
        }
    }
}

// ---------------- Aggregation: 32 lanes x float4 per node, 2 nodes/wave, idx prefetch ----------------
// out[v] = relu( sum_e wei[e]*g[bsrc[e]] + g[v]*dinv[v]^2 + bias )
__global__ __launch_bounds__(256) void agg_kernel(const float* __restrict__ g,
                                                  const int* __restrict__ offs,
                                                  const int* __restrict__ bsrc,
                                                  const float* __restrict__ wei,
                                                  const float* __restrict__ dinv,
                                                  const float* __restrict__ bias,
                                                  float* __restrict__ out, int n) {
    int half = threadIdx.x >> 5;   // 8 half-waves per block
    int lane = threadIdx.x & 31;   // 32 lanes x float4 = 512 B/row
    int node = blockIdx.x * 8 + half;
    if (node >= n) return;
    const float4* __restrict__ grow = (const float4*)g;
    int e0 = offs[node], e1 = offs[node + 1];
    float din = dinv[node];
    float s2 = din * din;
    float4 gs = grow[(long)node * 32 + lane];
    float4 acc;
    acc.x = gs.x * s2; acc.y = gs.y * s2; acc.z = gs.z * s2; acc.w = gs.w * s2;

    int e = e0;
    int nmain = (e1 - e0) & ~3;   // multiple of 4
    if (nmain > 0) {
        // prefetch first 4 indices/weights
        int   i0 = bsrc[e],     i1 = bsrc[e + 1], i2 = bsrc[e + 2], i3 = bsrc[e + 3];
        float w0 = wei[e],      w1 = wei[e + 1],  w2 = wei[e + 2],  w3 = wei[e + 3];
        for (e += 4; e < e0 + nmain; e += 4) {
            // issue gathers for current group
            float4 a0 = grow[(long)i0 * 32 + lane];
            float4 a1 = grow[(long)i1 * 32 + lane];
            float4 a2 = grow[(long)i2 * 32 + lane];
            float4 a3 = grow[(long)i3 * 32 + lane];
            // prefetch next group's indices/weights while gathers are in flight
            int   j0 = bsrc[e],     j1 = bsrc[e + 1], j2 = bsrc[e + 2], j3 = bsrc[e + 3];
            float v0 = wei[e],      v1 = wei[e + 1],  v2 = wei[e + 2],  v3 = wei[e + 3];
            acc.x = fmaf(a0.x, w0, acc.x); acc.y = fmaf(a0.y, w0, acc.y);
            acc.z = fmaf(a0.z, w0, acc.z); acc.w = fmaf(a0.w, w0, acc.w);
            acc.x = fmaf(a1.x, w1, acc.x); acc.y = fmaf(a1.y, w1, acc.y);
            acc.z = fmaf(a1.z, w1, acc.z); acc.w = fmaf(a1.w, w1, acc.w);
            acc.x = fmaf(a2.x, w2, acc.x); acc.y = fmaf(a2.y, w2, acc.y);
            acc.z = fmaf(a2.z, w2, acc.z); acc.w = fmaf(a2.w, w2, acc.w);
            acc.x = fmaf(a3.x, w3, acc.x); acc.y = fmaf(a3.y, w3, acc.y);
            acc.z = fmaf(a3.z, w3, acc.z); acc.w = fmaf(a3.w, w3, acc.w);
            i0 = j0; i1 = j1; i2 = j2; i3 = j3;
            w0 = v0; w1 = v1; w2 = v2; w3 = v3;
        }
        // drain last prefetched group
        float4 a0 = grow[(long)i0 * 32 + lane];
        float4 a1 = grow[(long)i1 * 32 + lane];
        float4 a2 = grow[(long)i2 * 32 + lane];
        float4 a3 = grow[(long)i3 * 32 + lane];
        acc.x = fmaf(a0.x, w0, acc.x); acc.y = fmaf(a0.y, w0, acc.y);
        acc.z = fmaf(a0.z, w0, acc.z); acc.w = fmaf(a0.w, w0, acc.w);
        acc.x = fmaf(a1.x, w1, acc.x); acc.y = fmaf(a1.y, w1, acc.y);
        acc.z = fmaf(a1.z, w1, acc.z); acc.w = fmaf(a1.w, w1, acc.w);
        acc.x = fmaf(a2.x, w2, acc.x); acc.y = fmaf(a2.y, w2, acc.y);
        acc.z = fmaf(a2.z, w2, acc.z); acc.w = fmaf(a2.w, w2, acc.w);
        acc.x = fmaf(a3.x, w3, acc.x); acc.y = fmaf(a3.y, w3, acc.y);
        acc.z = fmaf(a3.z, w3, acc.z); acc.w = fmaf(a3.w, w3, acc.w);
    }
    // tail (<4 edges)
    for (e = e0 + nmain; e < e1; ++e) {
        int s = bsrc[e];
        float w = wei[e];
        float4 a = grow[(long)s * 32 + lane];
        acc.x = fmaf(a.x, w, acc.x); acc.y = fmaf(a.y, w, acc.y);
        acc.z = fmaf(a.z, w, acc.z); acc.w = fmaf(a.w, w, acc.w);
    }
    float4 b4 = *(const float4*)&bias[lane * 4];
    float4 o;
    o.x = fmaxf(acc.x + b4.x, 0.f);
    o.y = fmaxf(acc.y + b4.y, 0.f);
    o.z = fmaxf(acc.z + b4.z, 0.f);
    o.w = fmaxf(acc.w + b4.w, 0.f);
    ((float4*)out)[(long)node * 32 + lane] = o;
}

// ---------------- Readout ----------------
__global__ __launch_bounds__(256) void final_kernel(const float* __restrict__ h,
                                                    const int* __restrict__ offs,
                                                    const int* __restrict__ bsrc,
                                                    const float* __restrict__ fcw,
                                                    const float* __restrict__ fcb,
                                                    float* __restrict__ out) {
    __shared__ float sred[256];
    int t = threadIdx.x;
    int e0 = offs[0], e1 = offs[1];
    float val;
    if (t < 128) {
        val = h[t] * fcw[t];
    } else {
        int col = t - 128;
        float s = 0.f;
        for (int e = e0; e < e1; ++e) s += h[(long)bsrc[e] * 128 + col];
        int cnt = e1 - e0; if (cnt < 1) cnt = 1;
        val = (s / (float)cnt) * fcw[t];
    }
    sred[t] = val;
    __syncthreads();
    for (int off = 128; off > 0; off >>= 1) {
        if (t < off) sred[t] += sred[t + off];
        __syncthreads();
    }
    if (t == 0) out[0] = sred[0] + fcb[0];
}

// ---------------- launch ----------------

extern "C" void kernel_launch(void* const* d_in, const int* in_sizes, int n_in,
                              void* d_out, int out_size, void* d_ws, size_t ws_size,
                              hipStream_t stream) {
    const float* x   = (const float*)d_in[0];
    const int*   ei  = (const int*)d_in[1];
    const float* w1  = (const float*)d_in[3];
    const float* b1  = (const float*)d_in[4];
    const float* w2  = (const float*)d_in[5];
    const float* b2  = (const float*)d_in[6];
    const float* fcw = (const float*)d_in[7];
    const float* fcb = (const float*)d_in[8];

    const int n = N_NODES;
    const int e = in_sizes[1] / 2;
    const int* src = ei;
    const int* dst = ei + e;

    char* ws = (char*)d_ws;
    size_t off = 0;
    auto take = [&](size_t bytes) -> void* {
        void* p = ws + off;
        off += (bytes + 255) & ~(size_t)255;
        return p;
    };
    const int nblk = (n + 1023) / 1024;   // 98
    int*   cnt  = (int*)  take((size_t)n * 4);
    int*   offs = (int*)  take((size_t)(n + 1) * 4);
    int*   cur  = (int*)  take((size_t)n * 4);
    float* dinv = (float*)take((size_t)n * 4);
    int*   bsum = (int*)  take((size_t)nblk * 4);
    int*   bpre = (int*)  take((size_t)nblk * 4);
    int*   bsrc = (int*)  take((size_t)e * 4);
    float* wei  = (float*)take((size_t)e * 4);
    float* bufA = (float*)take((size_t)n * NF * 4);
    float* bufB = (float*)take((size_t)n * NF * 4);
    (void)ws_size;

    hipMemsetAsync(cnt, 0, (size_t)n * 4, stream);
    count_kernel<<<(e / 4 + 255) / 256, 256, 0, stream>>>(dst, cnt, e);
    blocksum_kernel<<<nblk, 256, 0, stream>>>(cnt, bsum, n);
    bscan_kernel<<<1, 128, 0, stream>>>(bsum, bpre, offs, nblk, n);
    scatter_offs_kernel<<<nblk, 256, 0, stream>>>(cnt, bpre, offs, cur, n);
    dinv_kernel<<<(n + 255) / 256, 256, 0, stream>>>(cnt, dinv, n);
    fill_kernel<<<(e / 4 + 255) / 256, 256, 0, stream>>>(src, dst, dinv, cur, bsrc, wei, e);

    gemm_kernel<<<(n + 63) / 64, 256, 0, stream>>>(x, w1, bufA, n);
    agg_kernel<<<(n + 7) / 8, 256, 0, stream>>>(bufA, offs, bsrc, wei, dinv, b1, bufB, n);
    gemm_kernel<<<(n + 63) / 64, 256, 0, stream>>>(bufB, w2, bufA, n);
    agg_kernel<<<(n + 7) / 8, 256, 0, stream>>>(bufA, offs, bsrc, wei, dinv, b2, bufB, n);
    final_kernel<<<1, 256, 0, stream>>>(bufB, offs, bsrc, fcw, fcb, (float*)d_out);
}